// Round 2
// baseline (162.815 us; speedup 1.0000x reference)
//
#include <hip/hip_runtime.h>

// Vanilla tanh RNN scan: B=4096, T=1024, F=H=3.
// Layout: quad (4 lanes) handles 4 batches (C=4 chains per lane).
// Lane j owns hidden unit j (lane 3 duplicates unit 2 -> no exec-mask churn).
// The 4 chains interleave in the issue stream to hide dependent-chain latency
// (round-1 counters: VALUBusy 9.6% -> latency-bound with 1 chain/lane).
// tanh(p) = 1 - 2*rcp(exp2(s*p)+1), s=2*log2(e) folded into weights;
// recurrence carried on r = rcp(exp2(z)+1).

static constexpr int BATCH = 4096;
static constexpr int TLEN  = 1024;
static constexpr long HN_OFF = (long)BATCH * TLEN * 3;  // 12582912

#define SCL 2.8853900817779268f  // 2*log2(e)

template<int K>
__device__ __forceinline__ float qbcast(float v) {
  // broadcast lane K of each quad to all 4 lanes (quad_perm [K,K,K,K])
  int r = __builtin_amdgcn_update_dpp(0, __float_as_int(v), K * 0x55, 0xF, 0xF, true);
  return __int_as_float(r);
}

// component access into float4[6] with compile-time flat index
#define XCOMP(arr, ff) (((ff)&3)==0 ? arr[(ff)>>2].x : ((ff)&3)==1 ? arr[(ff)>>2].y : \
                        ((ff)&3)==2 ? arr[(ff)>>2].z : arr[(ff)>>2].w)

__global__ __launch_bounds__(64, 1) void rnn_scan_kernel(
    const float* __restrict__ X, const float* __restrict__ H0,
    const float* __restrict__ Wih, const float* __restrict__ Whh,
    const float* __restrict__ bih, const float* __restrict__ bhh,
    float* __restrict__ out)
{
  const int g  = blockIdx.x * 64 + threadIdx.x;  // 4096 lanes total
  const int q  = g >> 2;                         // quad id
  const int j  = g & 3;                          // unit index (3 = dup of 2)
  const int jr = (j < 3) ? j : 2;
  const int b0 = q * 4;                          // 4 batches per quad

  // Pre-scaled weights (shared across the lane's 4 chains).
  // z_j = cc + x.wi + r.wh, where h = 1-2r folds into wh/cc.
  const float wi0 = SCL * Wih[jr*3+0];
  const float wi1 = SCL * Wih[jr*3+1];
  const float wi2 = SCL * Wih[jr*3+2];
  const float a0 = Whh[jr*3+0], a1 = Whh[jr*3+1], a2 = Whh[jr*3+2];
  const float wh0 = -2.0f * SCL * a0;
  const float wh1 = -2.0f * SCL * a1;
  const float wh2 = -2.0f * SCL * a2;
  const float cc  = SCL * (bih[jr] + bhh[jr] + a0 + a1 + a2);

  float r0[4], r1[4], r2[4];
  const float4* Xv[4];
  float*        Yb[4];
#pragma unroll
  for (int c = 0; c < 4; ++c) {
    const int b = b0 + c;
    r0[c] = 0.5f - 0.5f * H0[b*3+0];
    r1[c] = 0.5f - 0.5f * H0[b*3+1];
    r2[c] = 0.5f - 0.5f * H0[b*3+2];
    Xv[c] = reinterpret_cast<const float4*>(X + (size_t)b * (TLEN*3));
    Yb[c] = out + (size_t)b * (TLEN*3);
  }

  // 8-step half-chunks, double buffered: 4 chains x 6 float4 x 2 = 192 VGPR.
  auto do_load = [&](float4 (&buf)[4][6], int t) {
#pragma unroll
    for (int c = 0; c < 4; ++c) {
      const float4* src = Xv[c] + (t * 3) / 4;   // t % 8 == 0 -> exact
#pragma unroll
      for (int i = 0; i < 6; ++i) buf[c][i] = src[i];
    }
  };

  auto do_chunk = [&](float4 (&buf)[4][6], int t) {
#pragma unroll
    for (int s = 0; s < 8; ++s) {
#pragma unroll
      for (int c = 0; c < 4; ++c) {
        const int f = s * 3;
        float x0 = XCOMP(buf[c], f+0);
        float x1 = XCOMP(buf[c], f+1);
        float x2 = XCOMP(buf[c], f+2);
        float zp = fmaf(x2, wi2, fmaf(x1, wi1, fmaf(x0, wi0, cc)));
        float z  = fmaf(r0[c], wh0, fmaf(r1[c], wh1, fmaf(r2[c], wh2, zp)));
        float e  = __builtin_amdgcn_exp2f(z);
        float rn = __builtin_amdgcn_rcpf(e + 1.0f);
        // own-unit output; lane 3 writes bit-identical duplicate of lane 2
        Yb[c][(size_t)(t + s) * 3 + jr] = fmaf(-2.0f, rn, 1.0f);
        r0[c] = qbcast<0>(rn);
        r1[c] = qbcast<1>(rn);
        r2[c] = qbcast<2>(rn);
      }
    }
  };

  float4 bufA[4][6], bufB[4][6];
  do_load(bufA, 0);
  for (int t = 0; t < TLEN; t += 16) {
    do_load(bufB, t + 8);
    do_chunk(bufA, t);
    if (t + 16 < TLEN) do_load(bufA, t + 16);
    do_chunk(bufB, t + 8);
  }

  // final hidden state h_n
#pragma unroll
  for (int c = 0; c < 4; ++c) {
    float rj = (j == 0) ? r0[c] : (j == 1) ? r1[c] : r2[c];
    out[HN_OFF + (size_t)(b0 + c) * 3 + jr] = fmaf(-2.0f, rj, 1.0f);
  }
}

extern "C" void kernel_launch(void* const* d_in, const int* in_sizes, int n_in,
                              void* d_out, int out_size, void* d_ws, size_t ws_size,
                              hipStream_t stream) {
  const float* X   = (const float*)d_in[0];
  const float* H0  = (const float*)d_in[1];
  const float* Wih = (const float*)d_in[2];
  const float* Whh = (const float*)d_in[3];
  const float* bih = (const float*)d_in[4];
  const float* bhh = (const float*)d_in[5];
  float* out = (float*)d_out;

  dim3 grid(BATCH / 64), block(64);   // 4096 lanes, C=4 batches/lane
  hipLaunchKernelGGL(rnn_scan_kernel, grid, block, 0, stream,
                     X, H0, Wih, Whh, bih, bhh, out);
}

// Round 3
// 73.461 us; speedup vs baseline: 2.2163x; 2.2163x over previous
//
#include <hip/hip_runtime.h>

// Vanilla tanh RNN scan: B=4096, T=1024, F=H=3.
// 4 lanes/batch (lane j = unit j, lane 3 duplicates unit 2), 256 waves = 1/CU.
// X staged HBM->LDS via global_load_lds (sink-proof, counted vmcnt, depth-2
// pipeline) -- rounds 1-2 proved hipcc sinks register prefetch buffers
// (VGPR_Count 64/124 << buffer size), exposing full memory latency per step.
// Chain: rn -> 2x DPP quad_perm -> 3 FMA -> exp2 -> add -> rcp (~40 cyc/step).
// tanh(p) = 1 - 2*rcp(exp2(s*p)+1), s = 2*log2(e) folded into weights;
// recurrence carried on rn = rcp(exp2(z)+1).

static constexpr int BATCH = 4096;
static constexpr int TLEN  = 1024;
static constexpr int ROW   = TLEN * 3;              // floats per batch row
static constexpr long HN_OFF = (long)BATCH * TLEN * 3;
static constexpr int NCH   = TLEN / 16;             // 64 chunks of 16 steps

#define SCL 2.8853900817779268f  // 2*log2(e)

#define AS_GLB __attribute__((address_space(1)))
#define AS_LDS __attribute__((address_space(3)))

template<int CTRL>
__device__ __forceinline__ float qdpp(float v) {
  int r = __builtin_amdgcn_update_dpp(0, __float_as_int(v), CTRL, 0xF, 0xF, true);
  return __int_as_float(r);
}

__global__ __launch_bounds__(64, 1) void rnn_scan_kernel(
    const float* __restrict__ X, const float* __restrict__ H0,
    const float* __restrict__ Wih, const float* __restrict__ Whh,
    const float* __restrict__ bih, const float* __restrict__ bhh,
    float* __restrict__ out)
{
  // [buf][float4-within-chunk][batch-within-wave]; one chunk = 16 steps = 12 float4
  __shared__ float4 xs[3][12][16];

  const int lane = threadIdx.x;
  const int wb   = blockIdx.x * 16;     // 16 batches per wave
  const int q    = lane >> 2;           // batch-in-wave for compute
  const int j    = lane & 3;            // unit (3 = duplicate of 2)
  const int jr   = (j < 3) ? j : 2;
  const int ja   = (jr == 2) ? 0 : jr + 1;   // (jr+1)%3
  const int jb   = (ja == 2) ? 0 : ja + 1;   // (jr+2)%3

  // Pre-scaled weights: z = cc + x.wi + rn*whS + rA*whA + rB*whB
  // (h = 1-2r folds the rowsum of Whh into cc and -2 into wh*)
  const float wi0 = SCL * Wih[jr*3+0];
  const float wi1 = SCL * Wih[jr*3+1];
  const float wi2 = SCL * Wih[jr*3+2];
  const float whS = -2.0f * SCL * Whh[jr*3+jr];
  const float whA = -2.0f * SCL * Whh[jr*3+ja];
  const float whB = -2.0f * SCL * Whh[jr*3+jb];
  const float cc  = SCL * (bih[jr] + bhh[jr] +
                           Whh[jr*3+0] + Whh[jr*3+1] + Whh[jr*3+2]);

  float rn = 0.5f - 0.5f * H0[(wb + q)*3 + jr];

  // staging: inst i, lane l fetches float4 (i*4 + (l>>4)) of batch (l&15)
  // -> lands at LDS slot l*16B = xs[buf][i*4 + (l>>4)][l&15]. 64B contiguous
  // per row per inst (sector-aligned), readback 2-way bank aliased (free).
  const float* gst = X + (size_t)(wb + (lane & 15)) * ROW + (lane >> 4) * 4;
  float* Yq = out + (size_t)(wb + q) * ROW + jr;

  auto stage = [&](int bs, int c) {
    const float* s0 = gst + c * 48;
#pragma unroll
    for (int i = 0; i < 3; ++i) {
      __builtin_amdgcn_global_load_lds((const AS_GLB void*)(s0 + i*16),
                                       (AS_LDS void*)&xs[bs][i*4][0], 16, 0, 0);
    }
  };

  stage(0, 0);
  stage(1, 1);

  int bufc = 0;
  for (int c = 0; c < NCH; ++c) {
    if (c + 2 < NCH) {
      int bs = (bufc >= 1) ? bufc - 1 : bufc + 2;   // (bufc+2)%3
      stage(bs, c + 2);
    }
    // Counted waits (stores count in vmcnt on CDNA):
    // c==0: only stage(1),stage(2) newer than stage(0) -> 6.
    // steady: stage(c+1) 3 + stores(c-1) 16 + stage(c+2) 3 = 22 newer ops
    // allowed outstanding; stage(c) and older forced complete (~free, >1200cy old).
    if (c == 0) asm volatile("s_waitcnt vmcnt(6)" ::: "memory");
    else        asm volatile("s_waitcnt vmcnt(22)" ::: "memory");

    const float4 (*cur)[16] = xs[bufc];
    float4 f0 = cur[0][q], f1 = cur[1][q],  f2 = cur[2][q];
    float4 f3 = cur[3][q], f4 = cur[4][q],  f5 = cur[5][q];
    float4 f6 = cur[6][q], f7 = cur[7][q],  f8 = cur[8][q];
    float4 f9 = cur[9][q], fa = cur[10][q], fb = cur[11][q];
    float* Yc = Yq + c * 48;

    // rA: lane j gets unit (j+1)%3 : quad_perm [1,2,0,0] = 0x09
    // rB: lane j gets unit (j+2)%3 : quad_perm [2,0,1,1] = 0x52
    // (lane 3 gets r0,r1 -> consistent duplicate of unit 2)
#define STEP1(x0,x1,x2,OFF) do { \
      float rA = qdpp<0x09>(rn); \
      float rB = qdpp<0x52>(rn); \
      float zp = fmaf((x2), wi2, fmaf((x1), wi1, fmaf((x0), wi0, cc))); \
      float z  = fmaf(rB, whB, fmaf(rA, whA, fmaf(rn, whS, zp))); \
      float e  = __builtin_amdgcn_exp2f(z); \
      rn = __builtin_amdgcn_rcpf(e + 1.0f); \
      Yc[OFF] = fmaf(-2.0f, rn, 1.0f); \
    } while (0)

    STEP1(f0.x,f0.y,f0.z,  0);
    STEP1(f0.w,f1.x,f1.y,  3);
    STEP1(f1.z,f1.w,f2.x,  6);
    STEP1(f2.y,f2.z,f2.w,  9);
    STEP1(f3.x,f3.y,f3.z, 12);
    STEP1(f3.w,f4.x,f4.y, 15);
    STEP1(f4.z,f4.w,f5.x, 18);
    STEP1(f5.y,f5.z,f5.w, 21);
    STEP1(f6.x,f6.y,f6.z, 24);
    STEP1(f6.w,f7.x,f7.y, 27);
    STEP1(f7.z,f7.w,f8.x, 30);
    STEP1(f8.y,f8.z,f8.w, 33);
    STEP1(f9.x,f9.y,f9.z, 36);
    STEP1(f9.w,fa.x,fa.y, 39);
    STEP1(fa.z,fa.w,fb.x, 42);
    STEP1(fb.y,fb.z,fb.w, 45);
#undef STEP1

    bufc = (bufc == 2) ? 0 : bufc + 1;
  }

  // final hidden state h_n (lane 3 duplicates lane 2's value, same address)
  out[HN_OFF + (size_t)(wb + q)*3 + jr] = fmaf(-2.0f, rn, 1.0f);
}

extern "C" void kernel_launch(void* const* d_in, const int* in_sizes, int n_in,
                              void* d_out, int out_size, void* d_ws, size_t ws_size,
                              hipStream_t stream) {
  const float* X   = (const float*)d_in[0];
  const float* H0  = (const float*)d_in[1];
  const float* Wih = (const float*)d_in[2];
  const float* Whh = (const float*)d_in[3];
  const float* bih = (const float*)d_in[4];
  const float* bhh = (const float*)d_in[5];
  float* out = (float*)d_out;

  dim3 grid(BATCH / 16), block(64);   // 256 waves, 16 batches/wave, 1 wave/CU
  hipLaunchKernelGGL(rnn_scan_kernel, grid, block, 0, stream,
                     X, H0, Wih, Whh, bih, bhh, out);
}

// Round 5
// 47.305 us; speedup vs baseline: 3.4418x; 1.5529x over previous
//
#include <hip/hip_runtime.h>

// Vanilla tanh RNN scan: B=4096, T=1024, F=H=3.
// Quad layout: 4 lanes/batch (lane j = unit j, lane 3 duplicates unit 2),
// 256 waves = 1/CU. Rounds 1-3 post-mortem: hipcc sinks every compiler-visible
// prefetch (VGPR_Count 64/124/44 << buffer size), exposing memory latency in
// the serial chain. Fix: inline-asm global loads/stores -> deterministic vmcnt
// stream, hand-counted waits (12 loads + 16 stores per 16-step chunk; steady
// wait = vmcnt(28)), depth-2 register double-buffer that cannot be sunk.
// Chain: rcp -> {dpp || fma} -> fma -> fma -> add -> exp2 -> rcp (~44 cyc).
// tanh(p) = 1 - 2*rcp(exp2(s*p)+1), s = 2*log2(e) folded into weights;
// recurrence carried on rn = rcp(exp2(z)+1).

static constexpr int BATCH = 4096;
static constexpr int TLEN  = 1024;
static constexpr int ROW   = TLEN * 3;
static constexpr long HN_OFF = (long)BATCH * TLEN * 3;

#define SCL 2.8853900817779268f  // 2*log2(e)

template<int CTRL>
__device__ __forceinline__ float qdpp(float v) {
  int r = __builtin_amdgcn_update_dpp(0, __float_as_int(v), CTRL, 0xF, 0xF, true);
  return __int_as_float(r);
}

#define LOADF4(dst, base, OFF) \
  asm volatile("global_load_dwordx4 %0, %1, off offset:" #OFF \
               : "=v"(dst) : "v"(base) : "memory")

#define STOREF(base, val, OFF) \
  asm volatile("global_store_dword %0, %1, off offset:" #OFF \
               :: "v"(base), "v"(val) : "memory")

#define WAITV(N) asm volatile("s_waitcnt vmcnt(" #N ")" ::: "memory")

// P is a float4[12] array name; all indices compile-time constants.
#define LOADCHUNK(P, PTR) do { \
  LOADF4(P[0], PTR, 0);    LOADF4(P[1], PTR, 16);   LOADF4(P[2], PTR, 32); \
  LOADF4(P[3], PTR, 48);   LOADF4(P[4], PTR, 64);   LOADF4(P[5], PTR, 80); \
  LOADF4(P[6], PTR, 96);   LOADF4(P[7], PTR, 112);  LOADF4(P[8], PTR, 128); \
  LOADF4(P[9], PTR, 144);  LOADF4(P[10], PTR, 160); LOADF4(P[11], PTR, 176); \
} while (0)

// one RNN step; x0..x2 are this step's inputs (registers), store via imm offset
#define STEPX(x0, x1, x2, SB, OFF) do { \
  float rA = qdpp<0x09>(rn); /* lane j <- unit (j+1)%3, lane3 mirrors lane2 */ \
  float rB = qdpp<0x52>(rn); /* lane j <- unit (j+2)%3 */ \
  float zp = fmaf((x2), wi2, fmaf((x1), wi1, fmaf((x0), wi0, cc))); \
  float z  = fmaf(rB, whB, fmaf(rA, whA, fmaf(rn, whS, zp))); \
  float e  = __builtin_amdgcn_exp2f(z); \
  rn = __builtin_amdgcn_rcpf(e + 1.0f); \
  float hv = fmaf(-2.0f, rn, 1.0f); \
  STOREF(SB, hv, OFF); \
} while (0)

#define DOCHUNK(P, SB) do { \
  STEPX(P[0].x, P[0].y, P[0].z,   SB, 0); \
  STEPX(P[0].w, P[1].x, P[1].y,   SB, 12); \
  STEPX(P[1].z, P[1].w, P[2].x,   SB, 24); \
  STEPX(P[2].y, P[2].z, P[2].w,   SB, 36); \
  STEPX(P[3].x, P[3].y, P[3].z,   SB, 48); \
  STEPX(P[3].w, P[4].x, P[4].y,   SB, 60); \
  STEPX(P[4].z, P[4].w, P[5].x,   SB, 72); \
  STEPX(P[5].y, P[5].z, P[5].w,   SB, 84); \
  STEPX(P[6].x, P[6].y, P[6].z,   SB, 96); \
  STEPX(P[6].w, P[7].x, P[7].y,   SB, 108); \
  STEPX(P[7].z, P[7].w, P[8].x,   SB, 120); \
  STEPX(P[8].y, P[8].z, P[8].w,   SB, 132); \
  STEPX(P[9].x, P[9].y, P[9].z,   SB, 144); \
  STEPX(P[9].w, P[10].x, P[10].y, SB, 156); \
  STEPX(P[10].z, P[10].w, P[11].x, SB, 168); \
  STEPX(P[11].y, P[11].z, P[11].w, SB, 180); \
} while (0)

__global__ __launch_bounds__(64, 1) void rnn_scan_kernel(
    const float* __restrict__ X, const float* __restrict__ H0,
    const float* __restrict__ Wih, const float* __restrict__ Whh,
    const float* __restrict__ bih, const float* __restrict__ bhh,
    float* __restrict__ out)
{
  const int lane = threadIdx.x;
  const int wb   = blockIdx.x * 16;     // 16 batches per wave
  const int q    = lane >> 2;           // batch-in-wave
  const int j    = lane & 3;            // unit (3 = duplicate of 2)
  const int jr   = (j < 3) ? j : 2;
  const int ja   = (jr == 2) ? 0 : jr + 1;
  const int jb   = (ja == 2) ? 0 : ja + 1;

  // pre-scaled weights: z = cc + x.wi + rn*whS + rA*whA + rB*whB
  const float wi0 = SCL * Wih[jr*3+0];
  const float wi1 = SCL * Wih[jr*3+1];
  const float wi2 = SCL * Wih[jr*3+2];
  const float whS = -2.0f * SCL * Whh[jr*3+jr];
  const float whA = -2.0f * SCL * Whh[jr*3+ja];
  const float whB = -2.0f * SCL * Whh[jr*3+jb];
  const float cc  = SCL * (bih[jr] + bhh[jr] +
                           Whh[jr*3+0] + Whh[jr*3+1] + Whh[jr*3+2]);

  float rn = 0.5f - 0.5f * H0[(wb + q)*3 + jr];

  const float* Xr = X + (size_t)(wb + q) * ROW;   // every lane loads its batch row
  float* Yq = out + (size_t)(wb + q) * ROW + jr;  // own-unit store base

  float4 A[12];
  float4 Bv[12];

  const float* pLa = Xr;        // even chunks
  const float* pLb = Xr + 48;   // odd chunks
  LOADCHUNK(A, pLa);  pLa += 96;
  LOADCHUNK(Bv, pLb); pLb += 96;
  float* pSa = Yq;
  float* pSb = Yq + 48;

  for (int k = 0; k < 32; ++k) {
    // chunk c = 2k (buffer A). Need L(2k): newer = st(2k-1) 16 + L(2k+1) 12.
    if (k == 0) { WAITV(12); } else { WAITV(28); }
    __builtin_amdgcn_sched_barrier(0);
    DOCHUNK(A, pSa);
    pSa += 96;
    if (k < 31) { LOADCHUNK(A, pLa); pLa += 96; }

    // chunk c = 2k+1 (buffer Bv). Need L(2k+1): newer = st(2k) 16 + L(2k+2) 12.
    if (k == 31) { WAITV(16); } else { WAITV(28); }
    __builtin_amdgcn_sched_barrier(0);
    DOCHUNK(Bv, pSb);
    pSb += 96;
    if (k < 31) { LOADCHUNK(Bv, pLb); pLb += 96; }
  }

  // final hidden state h_n (lane 3 writes bit-identical duplicate of lane 2)
  out[HN_OFF + (size_t)(wb + q)*3 + jr] = fmaf(-2.0f, rn, 1.0f);
}

extern "C" void kernel_launch(void* const* d_in, const int* in_sizes, int n_in,
                              void* d_out, int out_size, void* d_ws, size_t ws_size,
                              hipStream_t stream) {
  const float* X   = (const float*)d_in[0];
  const float* H0  = (const float*)d_in[1];
  const float* Wih = (const float*)d_in[2];
  const float* Whh = (const float*)d_in[3];
  const float* bih = (const float*)d_in[4];
  const float* bhh = (const float*)d_in[5];
  float* out = (float*)d_out;

  dim3 grid(BATCH / 16), block(64);   // 256 waves, 16 batches/wave, 1 wave/CU
  hipLaunchKernelGGL(rnn_scan_kernel, grid, block, 0, stream,
                     X, H0, Wih, Whh, bih, bhh, out);
}